// Round 8
// baseline (18.909 us; speedup 1.0000x reference)
//
#include <hip/hip_runtime.h>

// MipNeRF coarse cast + blur/inverse-CDF resample + fine cast.
// One 64-lane wave per ray; 256-thread blocks = 4 independent waves.
// Minimal-phase: LDS holds ONLY the sample payload table; frustums computed
// inline per output span (coarse: closed-form bins; fine: recomputed from
// payload). One wave_barrier total. NT float4 stores, DPP scan, rcp divides.

constexpr int B_RAYS = 8192;
constexpr int S      = 128;
constexpr int SP1    = 129;
constexpr float F32_EPS = 1.1920928955078125e-07f;
constexpr float USTEP   = (1.0f - F32_EPS) / 128.0f;
constexpr float R_SCALE = 128.0f / (1.0f - F32_EPS);

// flat output offsets (t_coarse, means_c, covs_c, t_fine, means_f, covs_f)
constexpr long long O_TC = 0;
constexpr long long O_MC = O_TC + (long long)B_RAYS * SP1;
constexpr long long O_CC = O_MC + (long long)B_RAYS * S * 3;
constexpr long long O_TF = O_CC + (long long)B_RAYS * S * 3;
constexpr long long O_MF = O_TF + (long long)B_RAYS * SP1;
constexpr long long O_CF = O_MF + (long long)B_RAYS * S * 3;

typedef float vf4 __attribute__((ext_vector_type(4)));

__device__ __forceinline__ float frcp(float x) { return __builtin_amdgcn_rcpf(x); }

template<int CTRL, int RM>
__device__ __forceinline__ float dpp_addf(float x) {
    int m = __builtin_amdgcn_update_dpp(0, __builtin_bit_cast(int, x),
                                        CTRL, RM, 0xF, true);
    return x + __builtin_bit_cast(float, m);
}
template<int CTRL>
__device__ __forceinline__ float dpp_movf(float x) {
    int m = __builtin_amdgcn_update_dpp(0, __builtin_bit_cast(int, x),
                                        CTRL, 0xF, 0xF, true);
    return __builtin_bit_cast(float, m);
}

__device__ __forceinline__ void st_nt(float* p, float v) {
    __builtin_nontemporal_store(v, p);
}
__device__ __forceinline__ void st_nt4(float* p, float4 v) {
    __builtin_nontemporal_store(__builtin_bit_cast(vf4, v),
                                reinterpret_cast<vf4*>(p));
}

// conical_frustum_to_gaussian, stable branch (rcp instead of exact div)
__device__ __forceinline__ void frustum(float t0, float t1, float rad2,
                                        float& tm, float& tv, float& rv)
{
    float mu  = 0.5f * (t0 + t1);
    float hw  = 0.5f * (t1 - t0);
    float mu2 = mu * mu, hw2 = hw * hw, hw4 = hw2 * hw2;
    float den  = fmaf(3.0f, mu2, hw2);
    float rden = frcp(den);
    tm = fmaf(2.0f * mu * hw2, rden, mu);
    tv = hw2 * (1.0f / 3.0f)
       - (4.0f / 15.0f) * (hw4 * fmaf(12.0f, mu2, -hw2)) * (rden * rden);
    rv = rad2 * (0.25f * mu2 + (5.0f / 12.0f) * hw2 - (4.0f / 15.0f) * hw4 * rden);
}

__device__ __forceinline__ float sel3(int c, float x, float y, float z)
{
    return (c == 0) ? x : ((c == 1) ? y : z);
}

// smallest s in [0,129] with (float)s * USTEP >= c  (exact predicate)
__device__ __forceinline__ int smin_of(float c)
{
    int s = (int)ceilf(c * R_SCALE);
    s = s < 0 ? 0 : (s > 129 ? 129 : s);
    #pragma unroll
    for (int it = 0; it < 2; ++it)
        if (s > 0 && (float)(s - 1) * USTEP >= c) --s;
    #pragma unroll
    for (int it = 0; it < 2; ++it)
        if (s < 129 && (float)s * USTEP < c) ++s;
    return s;
}

__global__ __launch_bounds__(256) void mipnerf_kernel(
    const float* __restrict__ origins,
    const float* __restrict__ directions,
    const float* __restrict__ radii,
    const float* __restrict__ nearp,
    const float* __restrict__ farp,
    const float* __restrict__ weights,
    float* __restrict__ out)
{
    const int tid = threadIdx.x;
    const int w   = tid >> 6;
    const int l   = tid & 63;
    const int b   = (blockIdx.x << 2) + w;

    __shared__ float4 s_pay[4][132];   // per-sample {c0, dc, b0, b1}

    const float2 wv = *reinterpret_cast<const float2*>(weights + (long long)b * S + 2*l);
    const float ox = origins[3*b+0], oy = origins[3*b+1], oz = origins[3*b+2];
    const float dx = directions[3*b+0], dy = directions[3*b+1], dz = directions[3*b+2];
    const float rad = radii[b];
    const float nv = nearp[b], fv = farp[b];

    const float rad2   = rad * rad;
    const float axx = dx*dx, ayy = dy*dy, azz = dz*dz;
    const float dmag2  = fmaxf(axx + ayy + azz, 1e-10f);
    const float rdmag2 = frcp(dmag2);
    const float nxx = 1.0f - axx * rdmag2;
    const float nyy = 1.0f - ayy * rdmag2;
    const float nzz = 1.0f - azz * rdmag2;

    auto bin = [&](int k) {
        float t = (float)k * (1.0f / 128.0f);
        return nv * (1.0f - t) + fv * t;     // bit-identical to reference
    };

    // ---- t_coarse out ----
    {
        float* ot = out + O_TC + (long long)b * SP1;
        st_nt(ot + l,      bin(l));
        st_nt(ot + l + 64, bin(l + 64));
        if (l == 0) st_nt(ot + 128, bin(128));
    }

    // ---- blur weights (lane holds w[2l], w[2l+1]); DPP +-1 shifts ----
    float wprev = dpp_movf<0x138>(wv.y);  if (l == 0)  wprev = wv.x;  // wave_shr:1
    float wnext = dpp_movf<0x130>(wv.x);  if (l == 63) wnext = wv.y;  // wave_shl:1
    float m0 = fmaxf(wprev, wv.x), m1 = fmaxf(wv.x, wv.y), m2 = fmaxf(wv.y, wnext);
    float wb0 = 0.5f * (m0 + m1) + 0.01f;
    float wb1 = 0.5f * (m1 + m2) + 0.01f;

    // ---- wave64 inclusive scan of pair sums via DPP ----
    float ps = wb0 + wb1;
    float x  = ps;
    x = dpp_addf<0x111, 0xF>(x);   // row_shr:1
    x = dpp_addf<0x112, 0xF>(x);   // row_shr:2
    x = dpp_addf<0x114, 0xF>(x);   // row_shr:4
    x = dpp_addf<0x118, 0xF>(x);   // row_shr:8
    x = dpp_addf<0x142, 0xA>(x);   // row_bcast15 -> rows 1,3
    x = dpp_addf<0x143, 0xC>(x);   // row_bcast31 -> rows 2,3
    float incl  = x;
    float total = __builtin_bit_cast(float,
        __builtin_amdgcn_readlane(__builtin_bit_cast(int, incl), 63));

    float pad   = fmaxf(1e-5f - total, 0.0f);
    float wstot = total + pad;
    float inv   = frcp(wstot);
    float padk  = pad * (1.0f / 128.0f);
    float excl  = incl - ps;

    // cdf entries this lane owns: A=cdf[2l], B=cdf[2l+1], C=cdf[2l+2]
    float Av = (l == 0)  ? 0.0f
             : fminf((excl + (float)(2*l) * padk) * inv, 1.0f);
    float Bv = fminf((excl + wb0 + (float)(2*l + 1) * padk) * inv, 1.0f);
    float Cv = (l == 63) ? 1.0f
             : fminf((incl + (float)(2*l + 2) * padk) * inv, 1.0f);

    // ---- run-scatter: interval k owns samples [smin(cdf[k]), smin(cdf[k+1])) ----
    int sm0 = smin_of(Av);
    int sm1 = smin_of(Bv);
    int sm2 = smin_of(Cv);                   // l==63: smin(1.0)=129 sentinel
    {
        float4 payA = make_float4(Av, Bv - Av, bin(2*l),     bin(2*l + 1));
        float4 payB = make_float4(Bv, Cv - Bv, bin(2*l + 1), bin(2*l + 2));
        for (int s2 = sm0; s2 < sm1; ++s2) s_pay[w][s2] = payA;
        for (int s2 = sm1; s2 < sm2; ++s2) s_pay[w][s2] = payB;
    }
    __builtin_amdgcn_wave_barrier();   // (wave-synchronous; ordering fence only)

    // emit float4 means + float4 covs for span m given t[k0],t[k0+1],t[k0+2]
    auto emit_span = [&](int m, float t0, float t1, float t2,
                         float* __restrict__ om, float* __restrict__ oc) {
        float tmA, tvA, rvA, tmB, tvB, rvB;
        frustum(t0, t1, rad2, tmA, tvA, rvA);
        frustum(t1, t2, rad2, tmB, tvB, rvB);
        int k0 = m + m / 3;            // floor(4m/3)
        int r  = 4*m - 3*k0;
        float4 mv, cv;
        #pragma unroll
        for (int e = 0; e < 4; ++e) {
            int  rc   = r + e;
            bool useB = rc >= 3;
            int  c    = useB ? rc - 3 : rc;
            float tm = useB ? tmB : tmA;
            float tv = useB ? tvB : tvA;
            float rv = useB ? rvB : rvA;
            (&mv.x)[e] = sel3(c, dx, dy, dz) * tm + sel3(c, ox, oy, oz);
            (&cv.x)[e] = tv * sel3(c, axx, ayy, azz) + rv * sel3(c, nxx, nyy, nzz);
        }
        st_nt4(om + 4*m, mv);
        st_nt4(oc + 4*m, cv);
    };

    // ---- coarse emit: fully inline, zero LDS ----
    {
        float* om = out + O_MC + (long long)b * 384;
        float* oc = out + O_CC + (long long)b * 384;
        int k0 = l + l / 3;
        emit_span(l, bin(k0), bin(k0 + 1), bin(k0 + 2), om, oc);
        if (l < 32) {
            int m2s = l + 64;
            int k0b = m2s + m2s / 3;
            emit_span(m2s, bin(k0b), bin(k0b + 1), bin(k0b + 2), om, oc);
        }
    }

    // ---- t_fine from payload (independent b128 reads) ----
    auto tf_of = [&](int s) -> float {
        float4 p = s_pay[w][s];
        float u  = (float)s * USTEP;
        float tt = (u - p.x) * frcp(p.y);
        if (!(tt == tt)) tt = 0.0f;              // nan_to_num
        tt = fminf(fmaxf(tt, 0.0f), 1.0f);       // clip (inf -> 1)
        return p.z + tt * (p.w - p.z);
    };
    {
        float* ot = out + O_TF + (long long)b * SP1;
        st_nt(ot + l,      tf_of(l));
        st_nt(ot + l + 64, tf_of(l + 64));
        if (l == 0) st_nt(ot + 128, tf_of(128));
    }

    // ---- fine emit: recompute t from payload per span (no 2nd LDS phase) ----
    {
        float* om = out + O_MF + (long long)b * 384;
        float* oc = out + O_CF + (long long)b * 384;
        int k0 = l + l / 3;
        emit_span(l, tf_of(k0), tf_of(k0 + 1), tf_of(k0 + 2), om, oc);
        if (l < 32) {
            int m2s = l + 64;
            int k0b = m2s + m2s / 3;
            emit_span(m2s, tf_of(k0b), tf_of(k0b + 1), tf_of(k0b + 2), om, oc);
        }
    }
}

extern "C" void kernel_launch(void* const* d_in, const int* in_sizes, int n_in,
                              void* d_out, int out_size, void* d_ws, size_t ws_size,
                              hipStream_t stream)
{
    const float* origins    = (const float*)d_in[0];
    const float* directions = (const float*)d_in[1];
    const float* radii      = (const float*)d_in[2];
    const float* nearp      = (const float*)d_in[3];
    const float* farp       = (const float*)d_in[4];
    const float* weights    = (const float*)d_in[5];
    float* out = (float*)d_out;

    mipnerf_kernel<<<B_RAYS / 4, 256, 0, stream>>>(
        origins, directions, radii, nearp, farp, weights, out);
}